// Round 13
// baseline (261.718 us; speedup 1.0000x reference)
//
#include <hip/hip_runtime.h>
#include <hip/hip_bf16.h>
#include <cstdint>

typedef __bf16 bf16;
typedef __bf16 bf16x8 __attribute__((ext_vector_type(8)));
typedef float floatx4 __attribute__((ext_vector_type(4)));

#define B_   4
#define L_   896
#define D_   2048
#define HQ_  32
#define HKV_ 8
#define HD_  64
#define NQKV 3072   /* 2048 q + 512 k + 512 v */
#define M_   3584   /* B_*L_ */

// async global->LDS, 16B per lane. LDS dst must be wave-uniform base + lane*16.
__device__ inline void gl_lds16(const bf16* g, bf16* l) {
    __builtin_amdgcn_global_load_lds(
        (const __attribute__((address_space(1))) void*)g,
        (__attribute__((address_space(3))) void*)l, 16, 0, 0);
}

__device__ inline void barrier_() {
    asm volatile("" ::: "memory");
    __builtin_amdgcn_s_barrier();
    asm volatile("" ::: "memory");
}

// ---------------------------------------------------------------------------
// Merged prep kernel (verified round 10): flat block ranges.
// ---------------------------------------------------------------------------
__device__ inline void tr_cvt_body(const float* __restrict__ in,
                                   ushort* __restrict__ out, int C, int R,
                                   int bx, int by, int tid, ushort (*t)[72]) {
    int tr = tid >> 4, tc = (tid & 15) << 2;
    long r0 = (long)by << 6, c0 = (long)bx << 6;
#pragma unroll
    for (int i = 0; i < 4; ++i) {
        float4 v = *(const float4*)&in[(r0 + tr + i * 16) * C + c0 + tc];
        union { bf16 b[4]; ushort4 u; } w;
        w.b[0] = (bf16)v.x; w.b[1] = (bf16)v.y; w.b[2] = (bf16)v.z; w.b[3] = (bf16)v.w;
        *(ushort4*)&t[tr + i * 16][tc] = w.u;
    }
    __syncthreads();
#pragma unroll
    for (int i = 0; i < 4; ++i) {
        ushort4 w;
        w.x = t[tc + 0][tr + i * 16];
        w.y = t[tc + 1][tr + i * 16];
        w.z = t[tc + 2][tr + i * 16];
        w.w = t[tc + 3][tr + i * 16];
        *(ushort4*)&out[(c0 + tr + i * 16) * R + r0 + tc] = w;
    }
}

__global__ __launch_bounds__(256) void prep_kernel(
    const float* __restrict__ x, const float* __restrict__ wq,
    const float* __restrict__ wk, const float* __restrict__ wv,
    const float* __restrict__ wo, const int* __restrict__ pos_ids,
    bf16* __restrict__ xb, bf16* __restrict__ wqkvT, bf16* __restrict__ woT,
    float2* __restrict__ cs) {
    __shared__ ushort t[64][72];
    const int d = blockIdx.x, tid = threadIdx.x;
    if (d < 7168) {
        long q = (long)d * 256 + tid;
        float4 v = ((const float4*)x)[q];
        union { bf16 b[4]; ushort4 u; } w;
        w.b[0] = (bf16)v.x; w.b[1] = (bf16)v.y; w.b[2] = (bf16)v.z; w.b[3] = (bf16)v.w;
        ((ushort4*)xb)[q] = w.u;
    } else if (d < 8192) {
        int e = d - 7168;
        tr_cvt_body(wq, (ushort*)wqkvT, 2048, 2048, e & 31, e >> 5, tid, t);
    } else if (d < 9216) {
        int e = d - 8192;
        tr_cvt_body(wo, (ushort*)woT, 2048, 2048, e & 31, e >> 5, tid, t);
    } else if (d < 9472) {
        int e = d - 9216;
        tr_cvt_body(wk, (ushort*)(wqkvT + 4194304L), 512, 2048, e & 7, e >> 3, tid, t);
    } else if (d < 9728) {
        int e = d - 9472;
        tr_cvt_body(wv, (ushort*)(wqkvT + 5242880L), 512, 2048, e & 7, e >> 3, tid, t);
    } else {
        int idx = (d - 9728) * 256 + tid;
        if (idx < L_ * 32) {
            int l = idx >> 5, i = idx & 31;
            float p = (float)pos_ids[l];
            float inv = exp2f(-(float)i * (13.287712379549449f / 32.0f));
            float a = p * inv;
            cs[idx] = make_float2(cosf(a), sinf(a));
        }
    }
}

// ---------------------------------------------------------------------------
// Merged post kernel: RoPE on QKV cols [0,2560) + V-cols transpose -> Vt.
// Disjoint QKV column ranges -> safe in one launch.
//   [0, 4480)      : rope (256 thr x 4 pairs, in place)
//   [4480, 4928)   : V transpose, e = d-4480 -> (by = e%14, bz = e/14)
// ---------------------------------------------------------------------------
__global__ __launch_bounds__(256) void post_kernel(
    bf16* __restrict__ QKV, const float2* __restrict__ cs,
    ushort* __restrict__ Vt) {
    __shared__ ushort t[64][72];
    const int d = blockIdx.x, tid = threadIdx.x;
    if (d < 4480) {
        int idx = d * 256 + tid;                    // [0, 3584*320)
        int m = idx / 320, g = idx - m * 320;       // 4-pair group; cols 8g..8g+7
        int l = m % L_;
        int hp = (g * 4) & 31;
        const float2* ct = &cs[l * 32 + hp];
        bf16* p = QKV + (long)m * NQKV + g * 8;
        bf16x8 v = *(bf16x8*)p;
        bf16x8 w;
#pragma unroll
        for (int i = 0; i < 4; i++) {
            float2 csv = ct[i];
            float x1 = (float)v[2 * i], x2 = (float)v[2 * i + 1];
            w[2 * i]     = (bf16)(x1 * csv.x - x2 * csv.y);
            w[2 * i + 1] = (bf16)(x1 * csv.y + x2 * csv.x);
        }
        *(bf16x8*)p = w;
    } else {
        const int e = d - 4480;
        const int by = e % 14, z = e / 14;          // z in [0,32)
        const ushort* ip = (const ushort*)(QKV + 2560)
                           + (long)(z >> 3) * (896L * 3072) + (long)(z & 7) * 64;
        ushort* op = Vt + (long)(z >> 3) * (8L * 57344) + (long)(z & 7) * 57344;
        int tr = tid >> 4, tc = (tid & 15) << 2;
        long r0 = (long)by << 6, c0 = 0;
#pragma unroll
        for (int i = 0; i < 4; ++i) {
            ushort4 v = *(const ushort4*)&ip[(r0 + tr + i * 16) * 3072 + c0 + tc];
            *(ushort4*)&t[tr + i * 16][tc] = v;
        }
        __syncthreads();
#pragma unroll
        for (int i = 0; i < 4; ++i) {
            ushort4 w;
            w.x = t[tc + 0][tr + i * 16];
            w.y = t[tc + 1][tr + i * 16];
            w.z = t[tc + 2][tr + i * 16];
            w.w = t[tc + 3][tr + i * 16];
            *(ushort4*)&op[(c0 + tr + i * 16) * 896 + r0 + tc] = w;
        }
    }
}

// ===========================================================================
// gemm224<JF,OUTF32>: unchanged (verified round 6). Full 256-block fill.
// ===========================================================================
template <int JF, int OUTF32>
__global__ __launch_bounds__(512, 2) void gemm224(
    const bf16* __restrict__ A, const bf16* __restrict__ Bt, void* __restrict__ C,
    int Ntot, int Ktot) {
    __shared__ bf16 ldsA[2][224 * 64];
    __shared__ bf16 ldsB[2][JF * 64 * 64];
    const int tid = threadIdx.x;
    const int lane = tid & 63;
    const int quad = lane >> 4, l16 = lane & 15;
    const int w = tid >> 6;
    const int wr = w >> 2, wc = w & 3;

    const int gx = gridDim.x;
    const int nwg = gx * gridDim.y;
    int orig = blockIdx.y * gx + blockIdx.x;
    int q8 = nwg >> 3, r8 = nwg & 7;
    int xcd = orig & 7, lid = orig >> 3;
    int wg = (xcd < r8 ? xcd * (q8 + 1) : r8 * (q8 + 1) + (xcd - r8) * q8) + lid;
    const long m0 = (long)(wg / gx) * 224;
    const long n0 = (long)(wg % gx) * (JF * 64);

    const long rowK = Ktot;
    const int srow = tid >> 3;
    const int scol = ((tid & 7) ^ (srow & 7)) << 3;
    const bf16* baseA = A  + (m0 + srow) * rowK + scol;
    const bf16* baseB = Bt + (n0 + srow) * rowK + scol;
    bf16* const dA = (bf16*)ldsA + tid * 8;
    bf16* const dB = (bf16*)ldsB + tid * 8;

    const int m7 = l16 & 7;
    const int col0 = ((0 + quad) ^ m7) << 3;
    const int col1 = ((4 + quad) ^ m7) << 3;
    const int abase = wr * 112 + l16;
    const int bbase = wc * (JF * 16) + l16;

    floatx4 acc[7][JF];
#pragma unroll
    for (int i = 0; i < 7; ++i)
#pragma unroll
        for (int j = 0; j < JF; ++j)
#pragma unroll
            for (int r = 0; r < 4; ++r) acc[i][j][r] = 0.f;

    bf16x8 af0[4][2], af1[3][2], bq[JF][2];

    const int T = Ktot >> 6;

    {
        gl_lds16(baseA,              dA);
        gl_lds16(baseA + 64 * rowK,  dA + 4096);
        gl_lds16(baseA + 128 * rowK, dA + 8192);
        if (tid < 256) gl_lds16(baseA + 192 * rowK, dA + 12288);
#pragma unroll
        for (int r = 0; r < JF; ++r) gl_lds16(baseB + r * 64 * rowK, dB + r * 4096);
#pragma unroll
        for (int r = 0; r < JF; ++r) gl_lds16(baseB + 64 + r * 64 * rowK,
                                              dB + JF * 4096 + r * 4096);
    }
    if (JF == 3) asm volatile("s_waitcnt vmcnt(3)" ::: "memory");
    else         asm volatile("s_waitcnt vmcnt(2)" ::: "memory");
    barrier_();

    for (int t = 0; t < T; ++t) {
        const int cur = t & 1, nxt = cur ^ 1;
        const bf16* pa = &ldsA[cur][0];
        const bf16* pb = &ldsB[cur][0];
        const long koff  = (long)(t + 1) * 64;
        const long koff2 = (long)(t + 2) * 64;

#pragma unroll
        for (int i = 0; i < 4; ++i) {
            const bf16* rp = &pa[(abase + i * 16) * 64];
            af0[i][0] = *(const bf16x8*)&rp[col0];
            af0[i][1] = *(const bf16x8*)&rp[col1];
        }
#pragma unroll
        for (int j = 0; j < JF; ++j) {
            const bf16* rp = &pb[(bbase + j * 16) * 64];
            bq[j][0] = *(const bf16x8*)&rp[col0];
            bq[j][1] = *(const bf16x8*)&rp[col1];
        }
        if (t + 1 < T) {
            const bf16* g = baseA + koff;
            bf16* l = dA + nxt * (224 * 64);
            gl_lds16(g,              l);
            gl_lds16(g + 64 * rowK,  l + 4096);
            gl_lds16(g + 128 * rowK, l + 8192);
            if (tid < 256) gl_lds16(g + 192 * rowK, l + 12288);
        }
        barrier_();
        asm volatile("s_waitcnt lgkmcnt(0)" ::: "memory");
        __builtin_amdgcn_sched_barrier(0);
        __builtin_amdgcn_s_setprio(1);
#pragma unroll
        for (int i = 0; i < 4; ++i)
#pragma unroll
            for (int j = 0; j < JF; ++j) {
                floatx4 c = acc[i][j];
                c = __builtin_amdgcn_mfma_f32_16x16x32_bf16(af0[i][0], bq[j][0], c, 0, 0, 0);
                c = __builtin_amdgcn_mfma_f32_16x16x32_bf16(af0[i][1], bq[j][1], c, 0, 0, 0);
                acc[i][j] = c;
            }
        __builtin_amdgcn_s_setprio(0);
        barrier_();

#pragma unroll
        for (int i = 0; i < 3; ++i) {
            const bf16* rp = &pa[(abase + (4 + i) * 16) * 64];
            af1[i][0] = *(const bf16x8*)&rp[col0];
            af1[i][1] = *(const bf16x8*)&rp[col1];
        }
        if (t + 2 < T) {
            const bf16* g = baseB + koff2;
            bf16* l = dB + cur * (JF * 64 * 64);
#pragma unroll
            for (int r = 0; r < JF; ++r) gl_lds16(g + r * 64 * rowK, l + r * 4096);
        }
        barrier_();
        asm volatile("s_waitcnt lgkmcnt(0)" ::: "memory");
        __builtin_amdgcn_sched_barrier(0);
        __builtin_amdgcn_s_setprio(1);
#pragma unroll
        for (int i = 0; i < 3; ++i)
#pragma unroll
            for (int j = 0; j < JF; ++j) {
                floatx4 c = acc[4 + i][j];
                c = __builtin_amdgcn_mfma_f32_16x16x32_bf16(af1[i][0], bq[j][0], c, 0, 0, 0);
                c = __builtin_amdgcn_mfma_f32_16x16x32_bf16(af1[i][1], bq[j][1], c, 0, 0, 0);
                acc[4 + i][j] = c;
            }
        __builtin_amdgcn_s_setprio(0);
        if (t + 2 < T) {
            if (JF == 3) asm volatile("s_waitcnt vmcnt(3)" ::: "memory");
            else         asm volatile("s_waitcnt vmcnt(2)" ::: "memory");
        } else {
            asm volatile("s_waitcnt vmcnt(0)" ::: "memory");
        }
        barrier_();
    }

#pragma unroll
    for (int i = 0; i < 7; ++i)
#pragma unroll
        for (int j = 0; j < JF; ++j)
#pragma unroll
            for (int r = 0; r < 4; ++r) {
                long m = m0 + wr * 112 + i * 16 + quad * 4 + r;
                long n = n0 + wc * (JF * 16) + j * 16 + l16;
                if (OUTF32) ((float*)C)[m * Ntot + n] = acc[i][j][r];
                else        ((bf16*)C)[m * Ntot + n] = (bf16)acc[i][j][r];
            }
}

// ---------------------------------------------------------------------------
// Flash attention, T12 swapped-QK (verified round 12) + UNPAIRED grid with
// LPT ordering: one q-tile per block, grid (14,16,4) = 896 blocks (3.5/CU,
// 4 co-resident at 16KB LDS / 116 VGPR — round 12's 448-block pairing left
// the new small footprint underused at 1.75 blocks/CU). Longest blocks
// dispatch first (x = 13 - blockIdx.x) so greedy scheduling backfills with
// short ones — LPT-style makespan without scheduler assumptions.
// ---------------------------------------------------------------------------
__global__ __launch_bounds__(256) void attn_kernel(
    const bf16* __restrict__ QKV,  // [M][3072]: q(rope'd) | k(rope'd) | v
    const bf16* __restrict__ Vt,   // [B][HKV][64][896]
    bf16* __restrict__ AO) {       // [M][2048]
    __shared__ bf16 Ks[64 * 64];
    __shared__ bf16 Vs[64 * 64];
    const int tid  = threadIdx.x;
    const int lane = tid & 63;
    const int wid  = tid >> 6;
    const int quad = lane >> 4, c = lane & 15;
    const int b = blockIdx.z;
    const int kvh = blockIdx.y >> 1, hp = blockIdx.y & 1;
    const int hq = kvh * 4 + hp * 2 + (wid >> 1);
    const int sub = wid & 1;               // q-row half within the 64-row tile
    const int x = 13 - blockIdx.x;         // LPT: longest first

    const bf16* Kb = QKV + ((long)(b * L_)) * NQKV + D_ + kvh * HD_;
    const bf16* Vb = Vt + ((long)(b * HKV_ + kvh)) * (HD_ * L_);

    const int srow = tid >> 3, schunk = (tid & 7) << 3;
    const int sslot = ((tid & 7) ^ (srow & 7)) << 3;    // swizzled LDS col
    const bf16* kp0 = &Kb[(long)srow * NQKV + schunk];
    const bf16* kp1 = &Kb[(long)(32 + srow) * NQKV + schunk];
    const bf16* vp0 = &Vb[(long)srow * L_ + schunk];
    const bf16* vp1 = &Vb[(long)(srow + 32) * L_ + schunk];

    // fragment-read swizzled cols: row&7 == c&7 for rows n*16+c
    const int m7 = c & 7;
    const int col0 = ((0 + quad) ^ m7) << 3;   // k-slice 0
    const int col1 = ((4 + quad) ^ m7) << 3;   // k-slice 1

    // gather constants
    const int srcA = ((quad & 1) << 5) + c;    // quad (quad&1)*2, same column
    const int srcB = srcA + 16;                // quad (quad&1)*2 + 1
    const int nsel = quad >> 1;                // dest-side n selector

    const floatx4 fzero = {0.f, 0.f, 0.f, 0.f};
    const float C1 = 0.18033688011112042f;   // 0.125 * log2(e)

    const int q0b = x * 64;
    const bf16* Qb = QKV + ((long)(b * L_ + q0b + sub * 32)) * NQKV + hq * HD_;

    bf16x8 qf[2][2];
#pragma unroll
    for (int a = 0; a < 2; a++) {
        qf[a][0] = *(const bf16x8*)&Qb[(long)(a * 16 + c) * NQKV + quad * 8];
        qf[a][1] = *(const bf16x8*)&Qb[(long)(a * 16 + c) * NQKV + 32 + quad * 8];
    }

    float lsum[2];
    floatx4 o[2][4];
#pragma unroll
    for (int a = 0; a < 2; a++) {
        lsum[a] = 0.f;
#pragma unroll
        for (int nt = 0; nt < 4; nt++)
#pragma unroll
            for (int r = 0; r < 4; r++) o[a][nt][r] = 0.f;
    }

    // fe per lane: query = q0b + sub*32 + a*16 + c
    int fe[2];
#pragma unroll
    for (int a = 0; a < 2; a++) {
        int l = q0b + sub * 32 + a * 16 + c;
        fe[a] = (l / 7 + 1) * 7;
    }
    const int femin = (q0b / 7 + 1) * 7;           // fe of block's first row
    const int kend  = ((q0b + 63) / 7 + 1) * 7;    // block-max frame end

    // prefetch tile 0
    bf16x8 kg0 = *(const bf16x8*)&kp0[0];
    bf16x8 kg1 = *(const bf16x8*)&kp1[0];
    bf16x8 vg0 = *(const bf16x8*)&vp0[0];
    bf16x8 vg1 = *(const bf16x8*)&vp1[0];

    for (int k0 = 0; k0 < kend; k0 += 64) {
        __syncthreads();   // previous tile's reads done before overwrite
        *(bf16x8*)&Ks[srow * 64 + sslot]        = kg0;
        *(bf16x8*)&Ks[(srow + 32) * 64 + sslot] = kg1;
        *(bf16x8*)&Vs[srow * 64 + sslot]        = vg0;
        *(bf16x8*)&Vs[(srow + 32) * 64 + sslot] = vg1;
        __syncthreads();

        const int kn = k0 + 64;
        if (kn < kend) {
            kg0 = *(const bf16x8*)&kp0[(long)kn * NQKV];
            kg1 = *(const bf16x8*)&kp1[(long)kn * NQKV];
            vg0 = *(const bf16x8*)&vp0[kn];
            vg1 = *(const bf16x8*)&vp1[kn];
        }

        bf16x8 kf[4][2];
#pragma unroll
        for (int n = 0; n < 4; n++) {
            const bf16* rp = &Ks[(n * 16 + c) * 64];
            kf[n][0] = *(bf16x8*)&rp[col0];
            kf[n][1] = *(bf16x8*)&rp[col1];
        }
        bf16x8 vf[4][2];
#pragma unroll
        for (int nt = 0; nt < 4; nt++) {
            const bf16* rp = &Vs[(nt * 16 + c) * 64];
            vf[nt][0] = *(bf16x8*)&rp[col0];
            vf[nt][1] = *(bf16x8*)&rp[col1];
        }
        const int masked = (k0 + 64 > femin);
#pragma unroll
        for (int a = 0; a < 2; a++) {
            // swapped QK: S^T[key = n*16+quad*4+r][query = ...a*16+c]
            floatx4 s[4];
#pragma unroll
            for (int n = 0; n < 4; n++) {
                s[n] = __builtin_amdgcn_mfma_f32_16x16x32_bf16(kf[n][0], qf[a][0], fzero, 0, 0, 0);
                s[n] = __builtin_amdgcn_mfma_f32_16x16x32_bf16(kf[n][1], qf[a][1], s[n], 0, 0, 0);
            }
            float e[4][4];
            if (masked) {
#pragma unroll
                for (int n = 0; n < 4; n++)
#pragma unroll
                    for (int r = 0; r < 4; r++) {
                        const int key = k0 + n * 16 + quad * 4 + r;
                        float v = exp2f(s[n][r] * C1);
                        v = (key < fe[a]) ? v : 0.f;
                        e[n][r] = v;
                        lsum[a] += v;
                    }
            } else {
#pragma unroll
                for (int n = 0; n < 4; n++)
#pragma unroll
                    for (int r = 0; r < 4; r++) {
                        float v = exp2f(s[n][r] * C1);
                        e[n][r] = v;
                        lsum[a] += v;
                    }
            }
            // pack e[n][0..3] -> 2 dwords per n
            uint pk[4][2];
#pragma unroll
            for (int n = 0; n < 4; n++) {
                union { bf16 h[2]; uint u; } t0, t1;
                t0.h[0] = (bf16)e[n][0]; t0.h[1] = (bf16)e[n][1];
                t1.h[0] = (bf16)e[n][2]; t1.h[1] = (bf16)e[n][3];
                pk[n][0] = t0.u; pk[n][1] = t1.u;
            }
            // shfl BOTH n-candidates, select at dest (nsel = quad>>1)
            union { uint u[4]; bf16x8 v; } pf0, pf1;
            {
                uint a0 = __shfl((int)pk[0][0], srcA);
                uint a1 = __shfl((int)pk[1][0], srcA);
                pf0.u[0] = nsel ? a1 : a0;
                uint b0 = __shfl((int)pk[0][1], srcA);
                uint b1 = __shfl((int)pk[1][1], srcA);
                pf0.u[1] = nsel ? b1 : b0;
                uint c0_ = __shfl((int)pk[0][0], srcB);
                uint c1_ = __shfl((int)pk[1][0], srcB);
                pf0.u[2] = nsel ? c1_ : c0_;
                uint d0 = __shfl((int)pk[0][1], srcB);
                uint d1 = __shfl((int)pk[1][1], srcB);
                pf0.u[3] = nsel ? d1 : d0;
                uint e0 = __shfl((int)pk[2][0], srcA);
                uint e1 = __shfl((int)pk[3][0], srcA);
                pf1.u[0] = nsel ? e1 : e0;
                uint f0 = __shfl((int)pk[2][1], srcA);
                uint f1 = __shfl((int)pk[3][1], srcA);
                pf1.u[1] = nsel ? f1 : f0;
                uint g0 = __shfl((int)pk[2][0], srcB);
                uint g1 = __shfl((int)pk[3][0], srcB);
                pf1.u[2] = nsel ? g1 : g0;
                uint h0 = __shfl((int)pk[2][1], srcB);
                uint h1 = __shfl((int)pk[3][1], srcB);
                pf1.u[3] = nsel ? h1 : h0;
            }
#pragma unroll
            for (int nt = 0; nt < 4; nt++) {
                o[a][nt] = __builtin_amdgcn_mfma_f32_16x16x32_bf16(pf0.v, vf[nt][0], o[a][nt], 0, 0, 0);
                o[a][nt] = __builtin_amdgcn_mfma_f32_16x16x32_bf16(pf1.v, vf[nt][1], o[a][nt], 0, 0, 0);
            }
        }
    }
    // lsum: sum the 4 quads (keys split across quads), then redistribute
#pragma unroll
    for (int a = 0; a < 2; a++) {
        lsum[a] += __shfl_xor(lsum[a], 16);
        lsum[a] += __shfl_xor(lsum[a], 32);
    }
#pragma unroll
    for (int a = 0; a < 2; a++)
#pragma unroll
        for (int r = 0; r < 4; r++) {
            // query row quad*4+r: lsum held at column quad*4+r (any quad)
            float ls = __shfl(lsum[a], (lane & 48) + quad * 4 + r);
            int l = q0b + sub * 32 + a * 16 + quad * 4 + r;
#pragma unroll
            for (int nt = 0; nt < 4; nt++)
                AO[((long)(b * L_ + l)) * D_ + hq * HD_ + nt * 16 + c] =
                    (bf16)(o[a][nt][r] / ls);
        }
}

// ---------------------------------------------------------------------------
extern "C" void kernel_launch(void* const* d_in, const int* in_sizes, int n_in,
                              void* d_out, int out_size, void* d_ws, size_t ws_size,
                              hipStream_t stream) {
    (void)in_sizes; (void)n_in; (void)out_size; (void)ws_size;
    const float* x  = (const float*)d_in[0];
    const float* wq = (const float*)d_in[1];
    const float* wk = (const float*)d_in[2];
    const float* wv = (const float*)d_in[3];
    const float* wo = (const float*)d_in[4];
    const int* pos  = (const int*)d_in[5];

    bf16* ws    = (bf16*)d_ws;
    bf16* xb    = ws;                   // [3584][2048] bf16 x  (reused as AO)
    bf16* wqkvT = ws + 7340032L;        // [3072][2048]  (wq^T | wk^T | wv^T)
    bf16* woT   = ws + 13631488L;       // [2048][2048]
    bf16* QKV   = ws + 17825792L;       // [3584][3072]
    bf16* Vt    = ws + 28835840L;       // [4][8][64][896]
    bf16* AO    = xb;
    float2* cs  = (float2*)(ws + 30670848L);  // [896][32]

    // merged prep: convert + 4 weight transposes + rope table (1 launch)
    prep_kernel<<<dim3(9840), 256, 0, stream>>>(x, wq, wk, wv, wo, pos,
                                                xb, wqkvT, woT, cs);

    // QKV projection: [3584][2048] x [3072][2048]^T -> [3584][3072] bf16
    gemm224<3, 0><<<dim3(16, 16), 512, 0, stream>>>(xb, wqkvT, QKV, NQKV, D_);

    // merged post: RoPE (cols <2560) + V transpose (cols >=2560) (1 launch)
    post_kernel<<<dim3(4928), 256, 0, stream>>>(QKV, cs, (ushort*)Vt);

    attn_kernel<<<dim3(14, 16, 4), 256, 0, stream>>>(QKV, Vt, AO);

    // output projection: [3584][2048] x [2048][2048]^T -> [3584][2048] fp32
    gemm224<2, 1><<<dim3(16, 16), 512, 0, stream>>>(AO, woT, d_out, D_, D_);
}

// Round 14
// 247.653 us; speedup vs baseline: 1.0568x; 1.0568x over previous
//
#include <hip/hip_runtime.h>
#include <hip/hip_bf16.h>
#include <cstdint>

typedef __bf16 bf16;
typedef __bf16 bf16x8 __attribute__((ext_vector_type(8)));
typedef float floatx4 __attribute__((ext_vector_type(4)));

#define B_   4
#define L_   896
#define D_   2048
#define HQ_  32
#define HKV_ 8
#define HD_  64
#define NQKV 3072   /* 2048 q + 512 k + 512 v */
#define M_   3584   /* B_*L_ */

// async global->LDS, 16B per lane. LDS dst must be wave-uniform base + lane*16.
__device__ inline void gl_lds16(const bf16* g, bf16* l) {
    __builtin_amdgcn_global_load_lds(
        (const __attribute__((address_space(1))) void*)g,
        (__attribute__((address_space(3))) void*)l, 16, 0, 0);
}

__device__ inline void barrier_() {
    asm volatile("" ::: "memory");
    __builtin_amdgcn_s_barrier();
    asm volatile("" ::: "memory");
}

// ---------------------------------------------------------------------------
// Merged prep kernel (verified round 10): flat block ranges.
// ---------------------------------------------------------------------------
__device__ inline void tr_cvt_body(const float* __restrict__ in,
                                   ushort* __restrict__ out, int C, int R,
                                   int bx, int by, int tid, ushort (*t)[72]) {
    int tr = tid >> 4, tc = (tid & 15) << 2;
    long r0 = (long)by << 6, c0 = (long)bx << 6;
#pragma unroll
    for (int i = 0; i < 4; ++i) {
        float4 v = *(const float4*)&in[(r0 + tr + i * 16) * C + c0 + tc];
        union { bf16 b[4]; ushort4 u; } w;
        w.b[0] = (bf16)v.x; w.b[1] = (bf16)v.y; w.b[2] = (bf16)v.z; w.b[3] = (bf16)v.w;
        *(ushort4*)&t[tr + i * 16][tc] = w.u;
    }
    __syncthreads();
#pragma unroll
    for (int i = 0; i < 4; ++i) {
        ushort4 w;
        w.x = t[tc + 0][tr + i * 16];
        w.y = t[tc + 1][tr + i * 16];
        w.z = t[tc + 2][tr + i * 16];
        w.w = t[tc + 3][tr + i * 16];
        *(ushort4*)&out[(c0 + tr + i * 16) * R + r0 + tc] = w;
    }
}

__global__ __launch_bounds__(256) void prep_kernel(
    const float* __restrict__ x, const float* __restrict__ wq,
    const float* __restrict__ wk, const float* __restrict__ wv,
    const float* __restrict__ wo, const int* __restrict__ pos_ids,
    bf16* __restrict__ xb, bf16* __restrict__ wqkvT, bf16* __restrict__ woT,
    float2* __restrict__ cs) {
    __shared__ ushort t[64][72];
    const int d = blockIdx.x, tid = threadIdx.x;
    if (d < 7168) {
        long q = (long)d * 256 + tid;
        float4 v = ((const float4*)x)[q];
        union { bf16 b[4]; ushort4 u; } w;
        w.b[0] = (bf16)v.x; w.b[1] = (bf16)v.y; w.b[2] = (bf16)v.z; w.b[3] = (bf16)v.w;
        ((ushort4*)xb)[q] = w.u;
    } else if (d < 8192) {
        int e = d - 7168;
        tr_cvt_body(wq, (ushort*)wqkvT, 2048, 2048, e & 31, e >> 5, tid, t);
    } else if (d < 9216) {
        int e = d - 8192;
        tr_cvt_body(wo, (ushort*)woT, 2048, 2048, e & 31, e >> 5, tid, t);
    } else if (d < 9472) {
        int e = d - 9216;
        tr_cvt_body(wk, (ushort*)(wqkvT + 4194304L), 512, 2048, e & 7, e >> 3, tid, t);
    } else if (d < 9728) {
        int e = d - 9472;
        tr_cvt_body(wv, (ushort*)(wqkvT + 5242880L), 512, 2048, e & 7, e >> 3, tid, t);
    } else {
        int idx = (d - 9728) * 256 + tid;
        if (idx < L_ * 32) {
            int l = idx >> 5, i = idx & 31;
            float p = (float)pos_ids[l];
            float inv = exp2f(-(float)i * (13.287712379549449f / 32.0f));
            float a = p * inv;
            cs[idx] = make_float2(cosf(a), sinf(a));
        }
    }
}

// ---------------------------------------------------------------------------
// Merged post kernel: RoPE on QKV cols [0,2560) + V-cols transpose -> Vt.
//   [0, 4480)      : rope (256 thr x 4 pairs, in place)
//   [4480, 4928)   : V transpose, e = d-4480 -> (by = e%14, z = e/14)
// ---------------------------------------------------------------------------
__global__ __launch_bounds__(256) void post_kernel(
    bf16* __restrict__ QKV, const float2* __restrict__ cs,
    ushort* __restrict__ Vt) {
    __shared__ ushort t[64][72];
    const int d = blockIdx.x, tid = threadIdx.x;
    if (d < 4480) {
        int idx = d * 256 + tid;                    // [0, 3584*320)
        int m = idx / 320, g = idx - m * 320;       // 4-pair group; cols 8g..8g+7
        int l = m % L_;
        int hp = (g * 4) & 31;
        const float2* ct = &cs[l * 32 + hp];
        bf16* p = QKV + (long)m * NQKV + g * 8;
        bf16x8 v = *(bf16x8*)p;
        bf16x8 w;
#pragma unroll
        for (int i = 0; i < 4; i++) {
            float2 csv = ct[i];
            float x1 = (float)v[2 * i], x2 = (float)v[2 * i + 1];
            w[2 * i]     = (bf16)(x1 * csv.x - x2 * csv.y);
            w[2 * i + 1] = (bf16)(x1 * csv.y + x2 * csv.x);
        }
        *(bf16x8*)p = w;
    } else {
        const int e = d - 4480;
        const int by = e % 14, z = e / 14;          // z in [0,32)
        const ushort* ip = (const ushort*)(QKV + 2560)
                           + (long)(z >> 3) * (896L * 3072) + (long)(z & 7) * 64;
        ushort* op = Vt + (long)(z >> 3) * (8L * 57344) + (long)(z & 7) * 57344;
        int tr = tid >> 4, tc = (tid & 15) << 2;
        long r0 = (long)by << 6, c0 = 0;
#pragma unroll
        for (int i = 0; i < 4; ++i) {
            ushort4 v = *(const ushort4*)&ip[(r0 + tr + i * 16) * 3072 + c0 + tc];
            *(ushort4*)&t[tr + i * 16][tc] = v;
        }
        __syncthreads();
#pragma unroll
        for (int i = 0; i < 4; ++i) {
            ushort4 w;
            w.x = t[tc + 0][tr + i * 16];
            w.y = t[tc + 1][tr + i * 16];
            w.z = t[tc + 2][tr + i * 16];
            w.w = t[tc + 3][tr + i * 16];
            *(ushort4*)&op[(c0 + tr + i * 16) * 896 + r0 + tc] = w;
        }
    }
}

// ===========================================================================
// gemm224<JF,OUTF32>: unchanged (verified round 6). Full 256-block fill.
// ===========================================================================
template <int JF, int OUTF32>
__global__ __launch_bounds__(512, 2) void gemm224(
    const bf16* __restrict__ A, const bf16* __restrict__ Bt, void* __restrict__ C,
    int Ntot, int Ktot) {
    __shared__ bf16 ldsA[2][224 * 64];
    __shared__ bf16 ldsB[2][JF * 64 * 64];
    const int tid = threadIdx.x;
    const int lane = tid & 63;
    const int quad = lane >> 4, l16 = lane & 15;
    const int w = tid >> 6;
    const int wr = w >> 2, wc = w & 3;

    const int gx = gridDim.x;
    const int nwg = gx * gridDim.y;
    int orig = blockIdx.y * gx + blockIdx.x;
    int q8 = nwg >> 3, r8 = nwg & 7;
    int xcd = orig & 7, lid = orig >> 3;
    int wg = (xcd < r8 ? xcd * (q8 + 1) : r8 * (q8 + 1) + (xcd - r8) * q8) + lid;
    const long m0 = (long)(wg / gx) * 224;
    const long n0 = (long)(wg % gx) * (JF * 64);

    const long rowK = Ktot;
    const int srow = tid >> 3;
    const int scol = ((tid & 7) ^ (srow & 7)) << 3;
    const bf16* baseA = A  + (m0 + srow) * rowK + scol;
    const bf16* baseB = Bt + (n0 + srow) * rowK + scol;
    bf16* const dA = (bf16*)ldsA + tid * 8;
    bf16* const dB = (bf16*)ldsB + tid * 8;

    const int m7 = l16 & 7;
    const int col0 = ((0 + quad) ^ m7) << 3;
    const int col1 = ((4 + quad) ^ m7) << 3;
    const int abase = wr * 112 + l16;
    const int bbase = wc * (JF * 16) + l16;

    floatx4 acc[7][JF];
#pragma unroll
    for (int i = 0; i < 7; ++i)
#pragma unroll
        for (int j = 0; j < JF; ++j)
#pragma unroll
            for (int r = 0; r < 4; ++r) acc[i][j][r] = 0.f;

    bf16x8 af0[4][2], af1[3][2], bq[JF][2];

    const int T = Ktot >> 6;

    {
        gl_lds16(baseA,              dA);
        gl_lds16(baseA + 64 * rowK,  dA + 4096);
        gl_lds16(baseA + 128 * rowK, dA + 8192);
        if (tid < 256) gl_lds16(baseA + 192 * rowK, dA + 12288);
#pragma unroll
        for (int r = 0; r < JF; ++r) gl_lds16(baseB + r * 64 * rowK, dB + r * 4096);
#pragma unroll
        for (int r = 0; r < JF; ++r) gl_lds16(baseB + 64 + r * 64 * rowK,
                                              dB + JF * 4096 + r * 4096);
    }
    if (JF == 3) asm volatile("s_waitcnt vmcnt(3)" ::: "memory");
    else         asm volatile("s_waitcnt vmcnt(2)" ::: "memory");
    barrier_();

    for (int t = 0; t < T; ++t) {
        const int cur = t & 1, nxt = cur ^ 1;
        const bf16* pa = &ldsA[cur][0];
        const bf16* pb = &ldsB[cur][0];
        const long koff  = (long)(t + 1) * 64;
        const long koff2 = (long)(t + 2) * 64;

#pragma unroll
        for (int i = 0; i < 4; ++i) {
            const bf16* rp = &pa[(abase + i * 16) * 64];
            af0[i][0] = *(const bf16x8*)&rp[col0];
            af0[i][1] = *(const bf16x8*)&rp[col1];
        }
#pragma unroll
        for (int j = 0; j < JF; ++j) {
            const bf16* rp = &pb[(bbase + j * 16) * 64];
            bq[j][0] = *(const bf16x8*)&rp[col0];
            bq[j][1] = *(const bf16x8*)&rp[col1];
        }
        if (t + 1 < T) {
            const bf16* g = baseA + koff;
            bf16* l = dA + nxt * (224 * 64);
            gl_lds16(g,              l);
            gl_lds16(g + 64 * rowK,  l + 4096);
            gl_lds16(g + 128 * rowK, l + 8192);
            if (tid < 256) gl_lds16(g + 192 * rowK, l + 12288);
        }
        barrier_();
        asm volatile("s_waitcnt lgkmcnt(0)" ::: "memory");
        __builtin_amdgcn_sched_barrier(0);
        __builtin_amdgcn_s_setprio(1);
#pragma unroll
        for (int i = 0; i < 4; ++i)
#pragma unroll
            for (int j = 0; j < JF; ++j) {
                floatx4 c = acc[i][j];
                c = __builtin_amdgcn_mfma_f32_16x16x32_bf16(af0[i][0], bq[j][0], c, 0, 0, 0);
                c = __builtin_amdgcn_mfma_f32_16x16x32_bf16(af0[i][1], bq[j][1], c, 0, 0, 0);
                acc[i][j] = c;
            }
        __builtin_amdgcn_s_setprio(0);
        barrier_();

#pragma unroll
        for (int i = 0; i < 3; ++i) {
            const bf16* rp = &pa[(abase + (4 + i) * 16) * 64];
            af1[i][0] = *(const bf16x8*)&rp[col0];
            af1[i][1] = *(const bf16x8*)&rp[col1];
        }
        if (t + 2 < T) {
            const bf16* g = baseB + koff2;
            bf16* l = dB + cur * (JF * 64 * 64);
#pragma unroll
            for (int r = 0; r < JF; ++r) gl_lds16(g + r * 64 * rowK, l + r * 4096);
        }
        barrier_();
        asm volatile("s_waitcnt lgkmcnt(0)" ::: "memory");
        __builtin_amdgcn_sched_barrier(0);
        __builtin_amdgcn_s_setprio(1);
#pragma unroll
        for (int i = 0; i < 3; ++i)
#pragma unroll
            for (int j = 0; j < JF; ++j) {
                floatx4 c = acc[4 + i][j];
                c = __builtin_amdgcn_mfma_f32_16x16x32_bf16(af1[i][0], bq[j][0], c, 0, 0, 0);
                c = __builtin_amdgcn_mfma_f32_16x16x32_bf16(af1[i][1], bq[j][1], c, 0, 0, 0);
                acc[4 + i][j] = c;
            }
        __builtin_amdgcn_s_setprio(0);
        if (t + 2 < T) {
            if (JF == 3) asm volatile("s_waitcnt vmcnt(3)" ::: "memory");
            else         asm volatile("s_waitcnt vmcnt(2)" ::: "memory");
        } else {
            asm volatile("s_waitcnt vmcnt(0)" ::: "memory");
        }
        barrier_();
    }

#pragma unroll
    for (int i = 0; i < 7; ++i)
#pragma unroll
        for (int j = 0; j < JF; ++j)
#pragma unroll
            for (int r = 0; r < 4; ++r) {
                long m = m0 + wr * 112 + i * 16 + quad * 4 + r;
                long n = n0 + wc * (JF * 16) + j * 16 + l16;
                if (OUTF32) ((float*)C)[m * Ntot + n] = acc[i][j][r];
                else        ((bf16*)C)[m * Ntot + n] = (bf16)acc[i][j][r];
            }
}

// ---------------------------------------------------------------------------
// Flash attention, T12 swapped-QK, PAIRED grid — exact round-12 version
// (measured best: 55.3 us). Round 13's unpaired/LPT variant regressed to
// 64.4 us (per-block fixed costs doubled, occupancy fell) — reverted.
// Block = 4 waves, one head-pair, passes (x, 13-x): uniform 15 tile-units.
// Grid (7,16,4) = 448 blocks. LDS 16 KB (no Ps — register gather for PV).
// ---------------------------------------------------------------------------
__global__ __launch_bounds__(256) void attn_kernel(
    const bf16* __restrict__ QKV,  // [M][3072]: q(rope'd) | k(rope'd) | v
    const bf16* __restrict__ Vt,   // [B][HKV][64][896]
    bf16* __restrict__ AO) {       // [M][2048]
    __shared__ bf16 Ks[64 * 64];
    __shared__ bf16 Vs[64 * 64];
    const int tid  = threadIdx.x;
    const int lane = tid & 63;
    const int wid  = tid >> 6;
    const int quad = lane >> 4, c = lane & 15;
    const int b = blockIdx.z;
    const int kvh = blockIdx.y >> 1, hp = blockIdx.y & 1;
    const int hq = kvh * 4 + hp * 2 + (wid >> 1);
    const int sub = wid & 1;               // q-row half within the 64-row tile
    const int xpair = blockIdx.x;          // 0..6

    const bf16* Kb = QKV + ((long)(b * L_)) * NQKV + D_ + kvh * HD_;
    const bf16* Vb = Vt + ((long)(b * HKV_ + kvh)) * (HD_ * L_);

    const int srow = tid >> 3, schunk = (tid & 7) << 3;
    const int sslot = ((tid & 7) ^ (srow & 7)) << 3;    // swizzled LDS col
    const bf16* kp0 = &Kb[(long)srow * NQKV + schunk];
    const bf16* kp1 = &Kb[(long)(32 + srow) * NQKV + schunk];
    const bf16* vp0 = &Vb[(long)srow * L_ + schunk];
    const bf16* vp1 = &Vb[(long)(srow + 32) * L_ + schunk];

    // fragment-read swizzled cols: row&7 == c&7 for rows n*16+c
    const int m7 = c & 7;
    const int col0 = ((0 + quad) ^ m7) << 3;   // k-slice 0
    const int col1 = ((4 + quad) ^ m7) << 3;   // k-slice 1

    // gather constants
    const int srcA = ((quad & 1) << 5) + c;    // quad (quad&1)*2, same column
    const int srcB = srcA + 16;                // quad (quad&1)*2 + 1
    const int nsel = quad >> 1;                // dest-side n selector

    const floatx4 fzero = {0.f, 0.f, 0.f, 0.f};
    const float C1 = 0.18033688011112042f;   // 0.125 * log2(e)

#pragma unroll 1
    for (int pass = 0; pass < 2; ++pass) {
        const int x = pass == 0 ? xpair : 13 - xpair;
        const int q0b = x * 64;
        const bf16* Qb = QKV + ((long)(b * L_ + q0b + sub * 32)) * NQKV + hq * HD_;

        bf16x8 qf[2][2];
#pragma unroll
        for (int a = 0; a < 2; a++) {
            qf[a][0] = *(const bf16x8*)&Qb[(long)(a * 16 + c) * NQKV + quad * 8];
            qf[a][1] = *(const bf16x8*)&Qb[(long)(a * 16 + c) * NQKV + 32 + quad * 8];
        }

        float lsum[2];
        floatx4 o[2][4];
#pragma unroll
        for (int a = 0; a < 2; a++) {
            lsum[a] = 0.f;
#pragma unroll
            for (int nt = 0; nt < 4; nt++)
#pragma unroll
                for (int r = 0; r < 4; r++) o[a][nt][r] = 0.f;
        }

        // fe per lane: query = q0b + sub*32 + a*16 + c
        int fe[2];
#pragma unroll
        for (int a = 0; a < 2; a++) {
            int l = q0b + sub * 32 + a * 16 + c;
            fe[a] = (l / 7 + 1) * 7;
        }
        const int femin = (q0b / 7 + 1) * 7;           // fe of block's first row
        const int kend  = ((q0b + 63) / 7 + 1) * 7;    // block-max frame end

        // prefetch tile 0 of this pass
        bf16x8 kg0 = *(const bf16x8*)&kp0[0];
        bf16x8 kg1 = *(const bf16x8*)&kp1[0];
        bf16x8 vg0 = *(const bf16x8*)&vp0[0];
        bf16x8 vg1 = *(const bf16x8*)&vp1[0];

        for (int k0 = 0; k0 < kend; k0 += 64) {
            __syncthreads();   // previous tile's reads done before overwrite
            *(bf16x8*)&Ks[srow * 64 + sslot]        = kg0;
            *(bf16x8*)&Ks[(srow + 32) * 64 + sslot] = kg1;
            *(bf16x8*)&Vs[srow * 64 + sslot]        = vg0;
            *(bf16x8*)&Vs[(srow + 32) * 64 + sslot] = vg1;
            __syncthreads();

            const int kn = k0 + 64;
            if (kn < kend) {
                kg0 = *(const bf16x8*)&kp0[(long)kn * NQKV];
                kg1 = *(const bf16x8*)&kp1[(long)kn * NQKV];
                vg0 = *(const bf16x8*)&vp0[kn];
                vg1 = *(const bf16x8*)&vp1[kn];
            }

            bf16x8 kf[4][2];
#pragma unroll
            for (int n = 0; n < 4; n++) {
                const bf16* rp = &Ks[(n * 16 + c) * 64];
                kf[n][0] = *(bf16x8*)&rp[col0];
                kf[n][1] = *(bf16x8*)&rp[col1];
            }
            bf16x8 vf[4][2];
#pragma unroll
            for (int nt = 0; nt < 4; nt++) {
                const bf16* rp = &Vs[(nt * 16 + c) * 64];
                vf[nt][0] = *(bf16x8*)&rp[col0];
                vf[nt][1] = *(bf16x8*)&rp[col1];
            }
            const int masked = (k0 + 64 > femin);
#pragma unroll
            for (int a = 0; a < 2; a++) {
                // swapped QK: S^T[key = n*16+quad*4+r][query = ...a*16+c]
                floatx4 s[4];
#pragma unroll
                for (int n = 0; n < 4; n++) {
                    s[n] = __builtin_amdgcn_mfma_f32_16x16x32_bf16(kf[n][0], qf[a][0], fzero, 0, 0, 0);
                    s[n] = __builtin_amdgcn_mfma_f32_16x16x32_bf16(kf[n][1], qf[a][1], s[n], 0, 0, 0);
                }
                float e[4][4];
                if (masked) {
#pragma unroll
                    for (int n = 0; n < 4; n++)
#pragma unroll
                        for (int r = 0; r < 4; r++) {
                            const int key = k0 + n * 16 + quad * 4 + r;
                            float v = exp2f(s[n][r] * C1);
                            v = (key < fe[a]) ? v : 0.f;
                            e[n][r] = v;
                            lsum[a] += v;
                        }
                } else {
#pragma unroll
                    for (int n = 0; n < 4; n++)
#pragma unroll
                        for (int r = 0; r < 4; r++) {
                            float v = exp2f(s[n][r] * C1);
                            e[n][r] = v;
                            lsum[a] += v;
                        }
                }
                // pack e[n][0..3] -> 2 dwords per n
                uint pk[4][2];
#pragma unroll
                for (int n = 0; n < 4; n++) {
                    union { bf16 h[2]; uint u; } t0, t1;
                    t0.h[0] = (bf16)e[n][0]; t0.h[1] = (bf16)e[n][1];
                    t1.h[0] = (bf16)e[n][2]; t1.h[1] = (bf16)e[n][3];
                    pk[n][0] = t0.u; pk[n][1] = t1.u;
                }
                // shfl BOTH n-candidates, select at dest (nsel = quad>>1)
                union { uint u[4]; bf16x8 v; } pf0, pf1;
                {
                    uint a0 = __shfl((int)pk[0][0], srcA);
                    uint a1 = __shfl((int)pk[1][0], srcA);
                    pf0.u[0] = nsel ? a1 : a0;
                    uint b0 = __shfl((int)pk[0][1], srcA);
                    uint b1 = __shfl((int)pk[1][1], srcA);
                    pf0.u[1] = nsel ? b1 : b0;
                    uint c0_ = __shfl((int)pk[0][0], srcB);
                    uint c1_ = __shfl((int)pk[1][0], srcB);
                    pf0.u[2] = nsel ? c1_ : c0_;
                    uint d0 = __shfl((int)pk[0][1], srcB);
                    uint d1 = __shfl((int)pk[1][1], srcB);
                    pf0.u[3] = nsel ? d1 : d0;
                    uint e0 = __shfl((int)pk[2][0], srcA);
                    uint e1 = __shfl((int)pk[3][0], srcA);
                    pf1.u[0] = nsel ? e1 : e0;
                    uint f0 = __shfl((int)pk[2][1], srcA);
                    uint f1 = __shfl((int)pk[3][1], srcA);
                    pf1.u[1] = nsel ? f1 : f0;
                    uint g0 = __shfl((int)pk[2][0], srcB);
                    uint g1 = __shfl((int)pk[3][0], srcB);
                    pf1.u[2] = nsel ? g1 : g0;
                    uint h0 = __shfl((int)pk[2][1], srcB);
                    uint h1 = __shfl((int)pk[3][1], srcB);
                    pf1.u[3] = nsel ? h1 : h0;
                }
#pragma unroll
                for (int nt = 0; nt < 4; nt++) {
                    o[a][nt] = __builtin_amdgcn_mfma_f32_16x16x32_bf16(pf0.v, vf[nt][0], o[a][nt], 0, 0, 0);
                    o[a][nt] = __builtin_amdgcn_mfma_f32_16x16x32_bf16(pf1.v, vf[nt][1], o[a][nt], 0, 0, 0);
                }
            }
        }
        // lsum: sum the 4 quads (keys split across quads), then redistribute
#pragma unroll
        for (int a = 0; a < 2; a++) {
            lsum[a] += __shfl_xor(lsum[a], 16);
            lsum[a] += __shfl_xor(lsum[a], 32);
        }
#pragma unroll
        for (int a = 0; a < 2; a++)
#pragma unroll
            for (int r = 0; r < 4; r++) {
                // query row quad*4+r: lsum held at column quad*4+r (any quad)
                float ls = __shfl(lsum[a], (lane & 48) + quad * 4 + r);
                int l = q0b + sub * 32 + a * 16 + quad * 4 + r;
#pragma unroll
                for (int nt = 0; nt < 4; nt++)
                    AO[((long)(b * L_ + l)) * D_ + hq * HD_ + nt * 16 + c] =
                        (bf16)(o[a][nt][r] / ls);
            }
    }
}

// ---------------------------------------------------------------------------
extern "C" void kernel_launch(void* const* d_in, const int* in_sizes, int n_in,
                              void* d_out, int out_size, void* d_ws, size_t ws_size,
                              hipStream_t stream) {
    (void)in_sizes; (void)n_in; (void)out_size; (void)ws_size;
    const float* x  = (const float*)d_in[0];
    const float* wq = (const float*)d_in[1];
    const float* wk = (const float*)d_in[2];
    const float* wv = (const float*)d_in[3];
    const float* wo = (const float*)d_in[4];
    const int* pos  = (const int*)d_in[5];

    bf16* ws    = (bf16*)d_ws;
    bf16* xb    = ws;                   // [3584][2048] bf16 x  (reused as AO)
    bf16* wqkvT = ws + 7340032L;        // [3072][2048]  (wq^T | wk^T | wv^T)
    bf16* woT   = ws + 13631488L;       // [2048][2048]
    bf16* QKV   = ws + 17825792L;       // [3584][3072]
    bf16* Vt    = ws + 28835840L;       // [4][8][64][896]
    bf16* AO    = xb;
    float2* cs  = (float2*)(ws + 30670848L);  // [896][32]

    // merged prep: convert + 4 weight transposes + rope table (1 launch)
    prep_kernel<<<dim3(9840), 256, 0, stream>>>(x, wq, wk, wv, wo, pos,
                                                xb, wqkvT, woT, cs);

    // QKV projection: [3584][2048] x [3072][2048]^T -> [3584][3072] bf16
    gemm224<3, 0><<<dim3(16, 16), 512, 0, stream>>>(xb, wqkvT, QKV, NQKV, D_);

    // merged post: RoPE (cols <2560) + V transpose (cols >=2560) (1 launch)
    post_kernel<<<dim3(4928), 256, 0, stream>>>(QKV, cs, (ushort*)Vt);

    attn_kernel<<<dim3(7, 16, 4), 256, 0, stream>>>(QKV, Vt, AO);

    // output projection: [3584][2048] x [2048][2048]^T -> [3584][2048] fp32
    gemm224<2, 1><<<dim3(16, 16), 512, 0, stream>>>(AO, woT, d_out, D_, D_);
}